// Round 7
// baseline (4231.028 us; speedup 1.0000x reference)
//
#include <hip/hip_runtime.h>
#include <math.h>

typedef _Float16 f16;
typedef f16  f16x8 __attribute__((ext_vector_type(8)));
typedef f16  f16x4 __attribute__((ext_vector_type(4)));
typedef float f32x4 __attribute__((ext_vector_type(4)));

#define NB 64
#define NC 16
#define NF 128
#define ND 256
#define NSTEP 60
#define GRID_ELEMS (NB*64*64*NC)   // 16 MB fp32
#define NPIX (NB*64*64)

#define KCONV 160                  // 9 taps * 16ch padded to 10 taps
#define HSS   136                  // hs row stride (f16) — proven conflict-balanced
#define RPS   17                   // redF row stride (fp32): [2][256][17]*4B == hs size

// weight buffer layout (f16 elements) inside d_out scratch region
#define OFF_CW 0             // [128][160]
#define OFF_W1 20480         // [256][128]
#define OFF_W2 53248         // [16][256]

// ---------------- init: grid ch0 = input, others 0 ----------------
__global__ void init_grid(const float* __restrict__ inp, float* __restrict__ g) {
    int i = blockIdx.x * 256 + threadIdx.x;
    if (i >= GRID_ELEMS) return;
    int c = i & 15;
    g[i] = (c == 0) ? inp[i >> 4] : 0.0f;
}

// ---------------- prep: f16 transposed weights ----------------
__global__ void prep_weights(const float* __restrict__ cw, const float* __restrict__ w1,
                             const float* __restrict__ w2, f16* __restrict__ wb) {
    int i = blockIdx.x * 256 + threadIdx.x;   // 57344 threads exactly
    float v; int off, idx;
    if (i < 20480) {                          // cwT[f][k], k = tap*16+c (tap9 zero)
        int f = i / 160, k = i - f * 160;
        v = (k < 144) ? cw[k * 128 + f] : 0.0f;
        off = OFF_CW; idx = i;
    } else if (i < 20480 + 32768) {           // w1T[j][f]
        int r = i - 20480;
        int j = r >> 7, f = r & 127;
        v = w1[f * 256 + j];
        off = OFF_W1; idx = r;
    } else {                                  // w2T[c][j]
        int r = i - 20480 - 32768;
        int c = r >> 8, j = r & 255;
        v = w2[j * 16 + c];
        off = OFF_W2; idx = r;
    }
    wb[off + idx] = (f16)v;
}

// ---------------- fused NCA step (pure-f16 MFMA, fp32 accumulate/state) ----------------
// R21 = R18 shell (16x16 tile, 1024 blocks, (256,2), 80KB LDS, 4 barriers) with
// 2x2 wave splits that HALVE the two big redundant LDS read streams:
//   conv : wave (wf,wp) = 64 filters x 8 px rows. B-reads 320->160 b128/block.
//          Per-(filter,pixel) kc-chains and operands unchanged -> bit-identical hs.
//   dense: wave (wj,wp) = 128 j x 128 px. hB held as 4-ptile quad per pass
//          (reads 256->128 b128/block); w1 streamed per-jt with REGISTER
//          DOUBLE-BUFFER one jt ahead (the prefetch R6 lacked).
//   redF : 2-deep fold [2][256][17] fp32 (= exact hs overlay); writes+reads halve.
// dense2 = 8-chain per wj + 2-fold: same reassociation class R1/R6 passed with
// identical absmax. Occupancy stays (256,2) — min_waves>=3 spills (R2/R3/R5).
__global__ __launch_bounds__(256, 2) void nca_step(
    const float* __restrict__ gin, float* __restrict__ gout,
    const f16* __restrict__ wb,
    const float* __restrict__ cb, const float* __restrict__ b1, const float* __restrict__ b2)
{
    // hs[256*136] (69632 B) + halo [18*18][16] (10368 B) = 80000 B
    // redF [2][256][17] fp32 (69632 B) overlays hs after dense phase.
    __shared__ f16 smem[40000];              // 80000 B
    f16* const hs   = smem;                  // 34816 elems
    f16* const halo = smem + 34816;          // [(hy*18+hx)]*16 + c
    float* const redF = (float*)smem;        // [2][256][RPS] fp32

    const int t    = threadIdx.x;
    const int w    = t >> 6;
    const int lane = t & 63;
    const int q    = lane >> 4;
    const int l16  = lane & 15;

    const int wp = w & 1;                    // pixel-half (rows wp*8 .. wp*8+7)
    const int wf = w >> 1;                   // conv filter-half (64 filters)
    const int wj = w >> 1;                   // dense j-half (128 j)

    // XCD swizzle: d = xcd + 8*(tl + 16*ip), image b = xcd*8 + ip
    const int d  = blockIdx.x;
    const int b  = ((d & 7) << 3) | (d >> 7);
    const int tl = (d >> 3) & 15;
    const int y0 = (tl >> 2) << 4;
    const int x0 = (tl & 3) << 4;

    const float* gb  = gin  + (size_t)b * 64 * 64 * 16;
    float*       gob = gout + (size_t)b * 64 * 64 * 16;

    const int fbase = wf << 6;               // conv: 64 filters (4 ft-tiles)
    const int jbase = wj << 7;               // dense: 128 j (8 jt-tiles)

    // ---- conv A prefetch for kc=0 (hide under halo staging) ----
    f16x8 cAc[4], cAn[4];
    #pragma unroll
    for (int ft = 0; ft < 4; ++ft)
        cAc[ft] = *(const f16x8*)(wb + OFF_CW +
            (size_t)(fbase + ft * 16 + l16) * KCONV + q * 8);

    // ---- stage halo (f16), zero-pad SAME; f32x4 global reads ----
    for (int i = t; i < 1296; i += 256) {    // 324 cells x 4 c-quads
        int c4 = (i & 3) << 2;
        int xy = i >> 2;
        int xx = xy % 18;
        int yy = xy / 18;
        int gy = y0 + yy - 1, gx = x0 + xx - 1;
        f32x4 v = {0.f, 0.f, 0.f, 0.f};
        if ((unsigned)gy < 64u && (unsigned)gx < 64u)
            v = *(const f32x4*)(gb + (gy * 64 + gx) * 16 + c4);
        f16x4 hv;
        hv.x = (f16)v.x; hv.y = (f16)v.y; hv.z = (f16)v.z; hv.w = (f16)v.w;
        *(f16x4*)(halo + xy * 16 + c4) = hv;
    }
    __syncthreads();

    // ========== conv 3x3x16 -> 128 (wave: 64 filters x 8 px rows) ==========
    {
        f32x4 acc[4][8];                     // 128 fp32/lane (AGPR-resident)
        #pragma unroll
        for (int ft = 0; ft < 4; ++ft) {
            f32x4 bias;
            bias.x = cb[fbase + ft * 16 + q * 4 + 0];
            bias.y = cb[fbase + ft * 16 + q * 4 + 1];
            bias.z = cb[fbase + ft * 16 + q * 4 + 2];
            bias.w = cb[fbase + ft * 16 + q * 4 + 3];
            #pragma unroll
            for (int p = 0; p < 8; ++p) acc[ft][p] = bias;
        }

        #pragma unroll 1
        for (int kc = 0; kc < 5; ++kc) {
            int kcn = (kc < 4) ? kc + 1 : 4;
            #pragma unroll
            for (int ft = 0; ft < 4; ++ft)   // prefetch next kc (L1-hot wb)
                cAn[ft] = *(const f16x8*)(wb + OFF_CW +
                    (size_t)(fbase + ft * 16 + l16) * KCONV + kcn * 32 + q * 8);
            int tap = kc * 2 + (q >> 1);
            if (tap > 8) tap = 8;            // k>=144: weights are zero
            int dy = tap / 3, dx = tap - dy * 3;
            #pragma unroll
            for (int p = 0; p < 8; ++p) {
                int hy = wp * 8 + p + dy;    // wave's own 8 rows
                int hx = l16 + dx;
                f16x8 bf = *(const f16x8*)(halo + (hy * 18 + hx) * 16 + (q & 1) * 8);
                #pragma unroll
                for (int ft = 0; ft < 4; ++ft)
                    acc[ft][p] = __builtin_amdgcn_mfma_f32_16x16x32_f16(cAc[ft], bf, acc[ft][p], 0, 0, 0);
            }
            #pragma unroll
            for (int ft = 0; ft < 4; ++ft) cAc[ft] = cAn[ft];
        }

        // relu in fp32, pack f16, write hs[px][f] (b64; same slots as R18)
        #pragma unroll
        for (int ft = 0; ft < 4; ++ft)
            #pragma unroll
            for (int p = 0; p < 8; ++p) {
                f32x4 a = acc[ft][p];
                f16x4 pk;
                pk.x = (f16)fmaxf(a.x, 0.0f);
                pk.y = (f16)fmaxf(a.y, 0.0f);
                pk.z = (f16)fmaxf(a.z, 0.0f);
                pk.w = (f16)fmaxf(a.w, 0.0f);
                *(f16x4*)(hs + ((wp * 8 + p) * 16 + l16) * HSS + fbase + ft * 16 + q * 4) = pk;
            }
    }
    __syncthreads();   // full hs published; halo dead

    // ---- tail-state prefetch (gin read-only): hide HBM under dense ----
    const size_t tpixb = ((size_t)(y0 + (t >> 4)) * 64 + (x0 + (t & 15))) * 16;
    const float a0 = gb[tpixb];              // exact fp32 ch0 (alive flag)
    f32x4 gv4[4];
    #pragma unroll
    for (int h = 0; h < 4; ++h) gv4[h] = *(const f32x4*)(gb + tpixb + h * 4);

    // ========== dense1+dense2 (wave: 128 j x 128 px), jt-prefetched ==========
    f32x4 dacc[8];                           // PARTIAL over this wave's 128 j
    #pragma unroll
    for (int p = 0; p < 8; ++p) { dacc[p].x = 0.f; dacc[p].y = 0.f; dacc[p].z = 0.f; dacc[p].w = 0.f; }

    #pragma unroll 1
    for (int pass = 0; pass < 2; ++pass) {   // 4 p-tiles per pass
        f16x8 hB[4][4];
        #pragma unroll
        for (int pp = 0; pp < 4; ++pp)
            #pragma unroll
            for (int kc = 0; kc < 4; ++kc)
                hB[pp][kc] = *(const f16x8*)(hs +
                    ((wp * 8 + pass * 4 + pp) * 16 + l16) * HSS + kc * 32 + q * 8);

        f16x8 dAc[4], dAn[4];
        #pragma unroll
        for (int kc = 0; kc < 4; ++kc)       // preload jt=0
            dAc[kc] = *(const f16x8*)(wb + OFF_W1 +
                (size_t)(jbase + l16) * 128 + kc * 32 + q * 8);

        #pragma unroll 1
        for (int jt = 0; jt < 8; ++jt) {
            int jn = (jt < 7) ? jt + 1 : 7;
            #pragma unroll
            for (int kc = 0; kc < 4; ++kc)   // prefetch next jt (L2-hot w1)
                dAn[kc] = *(const f16x8*)(wb + OFF_W1 +
                    (size_t)(jbase + jn * 16 + l16) * 128 + kc * 32 + q * 8);
            f32x4 b1v = *(const f32x4*)(b1 + jbase + jt * 16 + q * 4);
            f16x4 w2f = *(const f16x4*)(wb + OFF_W2 +
                (size_t)l16 * 256 + jbase + jt * 16 + q * 4);

            #pragma unroll
            for (int pp = 0; pp < 4; ++pp) {
                f32x4 a1 = b1v;
                #pragma unroll
                for (int kc = 0; kc < 4; ++kc)
                    a1 = __builtin_amdgcn_mfma_f32_16x16x32_f16(dAc[kc], hB[pp][kc], a1, 0, 0, 0);
                f16x4 pk;
                pk.x = (f16)fmaxf(a1.x, 0.0f);
                pk.y = (f16)fmaxf(a1.y, 0.0f);
                pk.z = (f16)fmaxf(a1.z, 0.0f);
                pk.w = (f16)fmaxf(a1.w, 0.0f);
                // dense1 D (row=j,col=px) IS the K=16 A-fragment (m=px,k=j);
                // dacc chains over jt ascending within this wj-half
                dacc[pass * 4 + pp] = __builtin_amdgcn_mfma_f32_16x16x16f16(pk, w2f, dacc[pass * 4 + pp], 0, 0, 0);
            }
            #pragma unroll
            for (int kc = 0; kc < 4; ++kc) dAc[kc] = dAn[kc];
        }
    }

    // ---- cross-wave reduction (2-deep: wj halves) ----
    __syncthreads();                         // all hs reads done -> redF may overwrite
    #pragma unroll
    for (int p = 0; p < 8; ++p)
        #pragma unroll
        for (int r = 0; r < 4; ++r) {
            int px = (wp * 8 + p) * 16 + q * 4 + r;      // global px 0..255
            redF[(wj * 256 + px) * RPS + l16] = dacc[p][r];
        }
    __syncthreads();

    // thread t = px, all 16 channels; masked residual update
    // (scalar redF reads: RPS=17 rows are 4B-aligned; stride-17 spreads banks)
    {
        const int px = t;
        const bool alive = (a0 > 0.1f);
        #pragma unroll
        for (int h = 0; h < 4; ++h) {
            const int ch = h * 4;
            f32x4 ov;
            #pragma unroll
            for (int i = 0; i < 4; ++i) {
                int c = ch + i;
                float sv = redF[(0 * 256 + px) * RPS + c]
                         + redF[(1 * 256 + px) * RPS + c];
                float nv = gv4[h][i];
                if (alive && c != 0) nv += sv + b2[c];
                ov[i] = nv;
            }
            *(f32x4*)(gob + tpixb + ch) = ov;
        }
    }
}

// ---------------- final softmax over channels 1..10 ----------------
__global__ void softmax_out(const float* __restrict__ g, float* __restrict__ out) {
    int pix = blockIdx.x * 256 + threadIdx.x;
    if (pix >= NPIX) return;
    const float* gp = g + (size_t)pix * 16;
    float v[10];
    float m = -1e30f;
    #pragma unroll
    for (int i = 0; i < 10; ++i) { v[i] = gp[1 + i]; m = fmaxf(m, v[i]); }
    float s = 0.f;
    #pragma unroll
    for (int i = 0; i < 10; ++i) { v[i] = __expf(v[i] - m); s += v[i]; }
    float inv = 1.0f / s;
    float* op = out + (size_t)pix * 10;
    #pragma unroll
    for (int i = 0; i < 10; ++i) op[i] = v[i] * inv;
}

extern "C" void kernel_launch(void* const* d_in, const int* in_sizes, int n_in,
                              void* d_out, int out_size, void* d_ws, size_t ws_size,
                              hipStream_t stream) {
    const float* inp = (const float*)d_in[0];
    const float* cw  = (const float*)d_in[1];
    const float* cb  = (const float*)d_in[2];
    const float* w1  = (const float*)d_in[3];
    const float* b1  = (const float*)d_in[4];
    const float* w2  = (const float*)d_in[5];
    const float* b2  = (const float*)d_in[6];
    float* out = (float*)d_out;

    // grid double-buffer in d_ws (32 MB, proven)
    float* g0 = (float*)d_ws;
    float* g1 = g0 + GRID_ELEMS;
    // f16 weights in d_out scratch (115 KB of 10.48 MB; softmax overwrites at end)
    f16* wb = (f16*)d_out;

    prep_weights<<<224, 256, 0, stream>>>(cw, w1, w2, wb);
    init_grid<<<(GRID_ELEMS + 255) / 256, 256, 0, stream>>>(inp, g0);

    float* bufs[2] = { g0, g1 };
    for (int s = 0; s < NSTEP; ++s) {
        nca_step<<<1024, 256, 0, stream>>>(bufs[s & 1], bufs[(s + 1) & 1],
                                           wb, cb, b1, b2);
    }
    // NSTEP=60 even -> final state in g0
    softmax_out<<<(NPIX + 255) / 256, 256, 0, stream>>>(g0, out);
}